// Round 4
// baseline (236.306 us; speedup 1.0000x reference)
//
#include <hip/hip_runtime.h>
#include <hip/hip_bf16.h>

#define BB 16
#define CIN 512
#define LL 2048
#define HEADS 4
#define EPSV 1e-5f

typedef __attribute__((ext_vector_type(8))) short bf16x8s;
typedef __attribute__((ext_vector_type(4))) float f32x4;

__device__ __forceinline__ unsigned short f2bf(float f) {
    union { float f; unsigned int i; } c; c.f = f;
    unsigned int x = c.i;
    unsigned int lsb = (x >> 16) & 1;
    x += 0x7fff + lsb;            // RNE
    return (unsigned short)(x >> 16);
}
__device__ __forceinline__ unsigned int pack2bf(float a, float b) {
    return (unsigned int)f2bf(a) | ((unsigned int)f2bf(b) << 16);
}

// ---------------- Kernel 0: weight repack fp32 -> bf16 ----------------
// Wpk: [cot 4][chunk 16][t 3][co 64][ci 40] bf16 (32 real ci + 8 pad)
#define WCH_U16 7680   // 3*64*40

__global__ __launch_bounds__(256) void prep_weights(
    const float* __restrict__ Wq, const float* __restrict__ Wk,
    const float* __restrict__ Wv, unsigned short* __restrict__ Wpk)
{
    int blk = blockIdx.x;             // 0..63 = cot*16 + chunk
    int cot = blk >> 4, chunk = blk & 15;
    int ci0 = chunk * 32;
    for (int i = threadIdx.x; i < WCH_U16; i += 256) {
        int t = i / 2560, r = i % 2560, co = r / 40, ci = r % 40;
        float val = 0.f;
        int cop = cot * 64 + co;
        if (ci < 32 && cop < 208) {
            int cig = ci0 + ci;
            if (cop < 64)        val = Wq[((size_t)cop * 512 + cig) * 3 + t];
            else if (cop < 80)   val = Wk[((size_t)(cop - 64) * 512 + cig) * 3 + t];
            else                 val = Wv[((size_t)(cop - 80) * 512 + cig) * 3 + t];
        }
        Wpk[(size_t)blk * WCH_U16 + i] = f2bf(val);
    }
}

// ---------------- Kernel 1: MFMA conv (q|k|v) + BN ----------------
// Block: 64 co x 256 n, 4 waves (each full 64co x 64n), K chunks of 32 ci.
#define XSTRIDE 20      // u32 per n-row (16 ci-pairs + 4 pad)

__global__ __launch_bounds__(256, 2) void conv_mfma(
    const float* __restrict__ x, const unsigned short* __restrict__ Wpk,
    const float* __restrict__ qg, const float* __restrict__ qb,
    const float* __restrict__ qm, const float* __restrict__ qv,
    const float* __restrict__ vg, const float* __restrict__ vb,
    const float* __restrict__ vm, const float* __restrict__ vvar,
    float* __restrict__ qbuf, float* __restrict__ kbuf, float* __restrict__ vbuf)
{
    __shared__ __align__(16) unsigned int xT[258 * XSTRIDE];     // 20640 B
    __shared__ __align__(16) unsigned short wA[WCH_U16];         // 15360 B
    __shared__ float sscale[64], sshift[64];

    const int tid = threadIdx.x;
    const int wave = tid >> 6, lane = tid & 63;
    const int kq = lane >> 4, lm = lane & 15;
    const int n0 = blockIdx.x * 256;
    const int cot = blockIdx.y;      // 4 co-tiles of 64
    const int b = blockIdx.z;

    if (tid < 64) {
        int cop = cot * 64 + tid;
        float sc = 1.f, sh = 0.f;
        if (cop < 64) {
            float g = qg[cop], be = qb[cop], m = qm[cop], va = qv[cop];
            sc = g * rsqrtf(va + EPSV); sh = be - m * sc;
        } else if (cop >= 80 && cop < 208) {
            int c = cop - 80;
            float g = vg[c], be = vb[c], m = vm[c], va = vvar[c];
            sc = g * rsqrtf(va + EPSV); sh = be - m * sc;
        }
        sscale[tid] = sc; sshift[tid] = sh;
    }

    f32x4 acc[4][4];
#pragma unroll
    for (int i = 0; i < 4; i++)
#pragma unroll
        for (int j = 0; j < 4; j++) acc[i][j] = (f32x4){0.f, 0.f, 0.f, 0.f};

    const float* xb = x + (size_t)b * CIN * LL;

    for (int chunk = 0; chunk < 16; chunk++) {
        __syncthreads();
        // weights: straight uint4 copy of prepacked image
        {
            const uint4* src = (const uint4*)(Wpk + (size_t)(cot * 16 + chunk) * WCH_U16);
            uint4* dst = (uint4*)wA;
            for (int i = tid; i < WCH_U16 / 8; i += 256) dst[i] = src[i];
        }
        // stage x: thread owns one n-row; 32 coalesced dword loads -> 16 packs -> 4 b128 writes
        const int ci0 = chunk * 32;
        {
            const float* xcol = xb + n0 + tid;
            unsigned int tmp[16];
#pragma unroll
            for (int p = 0; p < 16; p++) {
                float v0 = xcol[(size_t)(ci0 + 2 * p) * LL];
                float v1 = xcol[(size_t)(ci0 + 2 * p + 1) * LL];
                tmp[p] = pack2bf(v0, v1);
            }
            int row = tid + 1;
#pragma unroll
            for (int g = 0; g < 4; g++) {
                uint4 w = make_uint4(tmp[g * 4], tmp[g * 4 + 1], tmp[g * 4 + 2], tmp[g * 4 + 3]);
                *(uint4*)&xT[row * XSTRIDE + g * 4] = w;
            }
        }
        // halo rows 0 (n0-1) and 257 (n0+256)
        if (tid < 32) {
            int which = tid >> 4;            // 0 -> row0, 1 -> row257
            int p = tid & 15;
            int gn = which ? (n0 + 256) : (n0 - 1);
            float v0 = 0.f, v1 = 0.f;
            if (gn >= 0 && gn < LL) {
                v0 = xb[(size_t)(ci0 + 2 * p) * LL + gn];
                v1 = xb[(size_t)(ci0 + 2 * p + 1) * LL + gn];
            }
            xT[(which ? 257 : 0) * XSTRIDE + p] = pack2bf(v0, v1);
        }
        __syncthreads();

#pragma unroll
        for (int t = 0; t < 3; t++) {
            bf16x8s aF[4];
#pragma unroll
            for (int cof = 0; cof < 4; cof++)
                aF[cof] = *(const bf16x8s*)&wA[((t * 4 + cof) * 16 + lm) * 40 + kq * 8];
#pragma unroll
            for (int fn = 0; fn < 4; fn++) {
                int row = wave * 64 + fn * 16 + lm + t;
                bf16x8s bF = *(const bf16x8s*)&xT[row * XSTRIDE + kq * 4];
#pragma unroll
                for (int cof = 0; cof < 4; cof++)
                    acc[cof][fn] = __builtin_amdgcn_mfma_f32_16x16x32_bf16(aF[cof], bF, acc[cof][fn], 0, 0, 0);
            }
        }
    }

    // epilogue: C layout col(lane&15)=n, row(kq*4+reg)=co
#pragma unroll
    for (int cf = 0; cf < 4; cf++) {
#pragma unroll
        for (int fn = 0; fn < 4; fn++) {
#pragma unroll
            for (int r = 0; r < 4; r++) {
                int col = cf * 16 + kq * 4 + r;        // co_local
                int cop = cot * 64 + col;
                if (cop >= 208) continue;
                float val = acc[cf][fn][r] * sscale[col] + sshift[col];
                int nout = n0 + wave * 64 + fn * 16 + lm;
                if (cop < 64)
                    qbuf[((size_t)b * 64 + cop) * LL + nout] = val;
                else if (cop < 80)
                    kbuf[((size_t)b * 16 + (cop - 64)) * LL + nout] = val;
                else
                    vbuf[((size_t)b * 128 + (cop - 80)) * LL + nout] = val;
            }
        }
    }
}

// ---------------- Kernel 2: softmax over n, in place on kbuf ----------------
__global__ __launch_bounds__(256) void softmax_kernel(float* __restrict__ kbuf)
{
    const int row = blockIdx.x;                  // B*16 = 256 rows
    float* p = kbuf + (size_t)row * LL;
    const int tid = threadIdx.x;
    __shared__ float red[256];

    float vals[8];
    float vmax = -1e30f;
#pragma unroll
    for (int j = 0; j < 8; j++) {
        vals[j] = p[tid + j * 256];
        vmax = fmaxf(vmax, vals[j]);
    }
    red[tid] = vmax;
    __syncthreads();
    for (int s = 128; s > 0; s >>= 1) {
        if (tid < s) red[tid] = fmaxf(red[tid], red[tid + s]);
        __syncthreads();
    }
    float m = red[0];
    __syncthreads();
    float sum = 0.f;
#pragma unroll
    for (int j = 0; j < 8; j++) {
        vals[j] = __expf(vals[j] - m);
        sum += vals[j];
    }
    red[tid] = sum;
    __syncthreads();
    for (int s = 128; s > 0; s >>= 1) {
        if (tid < s) red[tid] += red[tid + s];
        __syncthreads();
    }
    float inv = 1.f / red[0];
#pragma unroll
    for (int j = 0; j < 8; j++) p[tid + j * 256] = vals[j] * inv;
}

// ---------------- Kernel 3: lcT[b][v][k] = sum_n sm[b][k][n]*v[b][v][n] ------
// wave task = (b, k-quad, v-group-of-8), full n sweep, float4 loads
__global__ __launch_bounds__(256) void lambdac_kernel(
    const float* __restrict__ sm, const float* __restrict__ vbuf,
    float* __restrict__ lcT)
{
    const int wave = threadIdx.x >> 6;
    const int lane = threadIdx.x & 63;
    const int task = blockIdx.x * 4 + wave;   // 16*4*16 = 1024 tasks
    const int b = task >> 6;
    const int rem = task & 63;
    const int kq4 = rem >> 4;                 // k = kq4*4 .. +3
    const int vg = rem & 15;                  // v = vg*8 .. +7
    const float* ps = sm + ((size_t)b * 16 + kq4 * 4) * LL;
    const float* pv = vbuf + ((size_t)b * 128 + vg * 8) * LL;
    float acc[4][8];
#pragma unroll
    for (int ki = 0; ki < 4; ki++)
#pragma unroll
        for (int vi = 0; vi < 8; vi++) acc[ki][vi] = 0.f;

#pragma unroll 2
    for (int j = 0; j < 8; j++) {
        int n = (j * 64 + lane) * 4;
        float4 s4[4];
#pragma unroll
        for (int ki = 0; ki < 4; ki++)
            s4[ki] = *(const float4*)&ps[(size_t)ki * LL + n];
#pragma unroll
        for (int vi = 0; vi < 8; vi++) {
            float4 v4 = *(const float4*)&pv[(size_t)vi * LL + n];
#pragma unroll
            for (int ki = 0; ki < 4; ki++)
                acc[ki][vi] += s4[ki].x * v4.x + s4[ki].y * v4.y
                             + s4[ki].z * v4.z + s4[ki].w * v4.w;
        }
    }
#pragma unroll
    for (int ki = 0; ki < 4; ki++)
#pragma unroll
        for (int vi = 0; vi < 8; vi++) {
#pragma unroll
            for (int off = 32; off > 0; off >>= 1)
                acc[ki][vi] += __shfl_xor(acc[ki][vi], off, 64);
        }
    if (lane == 0) {
#pragma unroll
        for (int vi = 0; vi < 8; vi++)
#pragma unroll
            for (int ki = 0; ki < 4; ki++)
                lcT[((size_t)b * 128 + vg * 8 + vi) * 16 + kq4 * 4 + ki] = acc[ki][vi];
    }
}

// ---------------- Kernel 4: output ----------------
// out[b][h*128+v][n] = sum_k q[b][h*16+k][n]*lcT[b][v][k] + (sum_k q*emb[k]) * v[b][v][n]
// lcT/emb read as block-uniform (scalar) loads; q[16] in VGPRs.
__global__ __launch_bounds__(256) void final_kernel(
    const float* __restrict__ qbuf, const float* __restrict__ vbuf,
    const float* __restrict__ lcT, const float* __restrict__ emb,
    float* __restrict__ out)
{
    const int tid = threadIdx.x;
    const int n0 = blockIdx.x * 256;    // 8 tiles
    const int h = blockIdx.y;           // 4
    const int b = blockIdx.z;           // 16
    const int n = n0 + tid;

    float q[16];
    float s = 0.f;
#pragma unroll
    for (int k = 0; k < 16; k++) {
        q[k] = qbuf[((size_t)b * 64 + h * 16 + k) * LL + n];
        s += q[k] * emb[k];
    }
    const float* lcb = lcT + (size_t)b * 2048;   // [v][16]
    const float* pv = vbuf + (size_t)b * 128 * LL + n;
    float* po = out + ((size_t)b * 512 + h * 128) * LL + n;
#pragma unroll 4
    for (int v = 0; v < 128; v++) {
        float lam = 0.f;
#pragma unroll
        for (int k = 0; k < 16; k++) lam += q[k] * lcb[v * 16 + k];
        po[(size_t)v * LL] = lam + s * pv[(size_t)v * LL];
    }
}

extern "C" void kernel_launch(void* const* d_in, const int* in_sizes, int n_in,
                              void* d_out, int out_size, void* d_ws, size_t ws_size,
                              hipStream_t stream)
{
    const float* x   = (const float*)d_in[0];
    const float* Wq  = (const float*)d_in[1];
    const float* qg  = (const float*)d_in[2];
    const float* qb  = (const float*)d_in[3];
    const float* qm  = (const float*)d_in[4];
    const float* qv  = (const float*)d_in[5];
    const float* Wk  = (const float*)d_in[6];
    const float* Wv  = (const float*)d_in[7];
    const float* vg  = (const float*)d_in[8];
    const float* vb  = (const float*)d_in[9];
    const float* vm  = (const float*)d_in[10];
    const float* vva = (const float*)d_in[11];
    const float* emb = (const float*)d_in[12];
    float* out = (float*)d_out;

    float* qbuf = (float*)d_ws;                        // 16*64*2048
    float* kbuf = qbuf + (size_t)BB * 64 * LL;         // 16*16*2048
    float* vbuf = kbuf + (size_t)BB * 16 * LL;         // 16*128*2048
    float* lcT  = vbuf + (size_t)BB * 128 * LL;        // 16*128*16
    unsigned short* Wpk = (unsigned short*)(lcT + (size_t)BB * 128 * 16);

    hipLaunchKernelGGL(prep_weights, dim3(64), dim3(256), 0, stream, Wq, Wk, Wv, Wpk);

    hipLaunchKernelGGL(conv_mfma, dim3(8, 4, 16), dim3(256), 0, stream,
                       x, Wpk, qg, qb, qm, qv, vg, vb, vm, vva,
                       qbuf, kbuf, vbuf);

    hipLaunchKernelGGL(softmax_kernel, dim3(BB * 16), dim3(256), 0, stream, kbuf);

    hipLaunchKernelGGL(lambdac_kernel, dim3(256), dim3(256), 0, stream,
                       kbuf, vbuf, lcT);

    hipLaunchKernelGGL(final_kernel, dim3(8, HEADS, BB), dim3(256), 0, stream,
                       qbuf, vbuf, lcT, emb, out);
}